// Round 10
// baseline (361.919 us; speedup 1.0000x reference)
//
#include <hip/hip_runtime.h>

// VQ nearest-neighbor, two-pass, swapped-operand MFMA (round 10).
//  pass1: mfma(A=codebook_h, B=z_h): lane holds candidates for its own z-row in
//         acc regs; per-panel ext MFMA adds -csq/2; in-lane TOP-3 fold;
//         2-kt barrier intervals (16 MFMA/interval), setprio, counted prefetch.
//  gather: certify winner / exact-rescore pool (bucket top-2, indices known) /
//          flag row only if bucket 3rd-best within margin (or pool > 6).
//  rescue: exact fp32 re-scan of flagged rows (~1-2%).
// score(k) = csq[k] - 2*z.c_k = -2*acc  (argmin score == argmax acc)

constexpr int Bn = 8192;
constexpr int Kn = 8192;
constexpr int Dn = 512;

using half8  = __attribute__((ext_vector_type(8)))  _Float16;
using f32x16 = __attribute__((ext_vector_type(16))) float;

// workspace layout (bytes), ~29.3MB
#define WS_CSQ  0u
#define WS_ZSQ  (32u*1024u)
#define WS_MAX  (64u*1024u)
#define WS_CNT  (64u*1024u + 64u)
#define WS_WL   (96u*1024u)
#define WS_P1   (1u*1024u*1024u)   // float4 [8192][64] (s1,i1,s2,i2) = 8MB
#define WS_P3   (9u*1024u*1024u)   // float2 [8192][64] (s3,0) = 4MB
#define WS_P2R  WS_P1              // rescue p2 aliases P1 (dead after gather)
#define WS_CIMG (13u*1024u*1024u)  // codebook h image: 64 blk x 32 kt x 4KB = 8MB
#define WS_ZIMG (21u*1024u*1024u)  // z h image:        32 blk x 32 kt x 8KB = 8MB
#define WS_CEXT (29u*1024u*1024u)  // ext frags: 64 blk x 4 grp x 1KB = 256KB

typedef __attribute__((address_space(3))) void       as3_void;
typedef const __attribute__((address_space(1))) void as1_cvoid;

#define MFMA16 __builtin_amdgcn_mfma_f32_32x32x16_f16

// ---------------- prep_sums: row sumsq (exact fp32) + cmax -------------------
__global__ __launch_bounds__(256) void prep_sums(const float* __restrict__ Z,
                                                 const float* __restrict__ Cb,
                                                 char* __restrict__ ws) {
  const int w = threadIdx.x >> 6, lane = threadIdx.x & 63;
  const int rid = blockIdx.x * 4 + w;  // 0..16383
  if (blockIdx.x == 0 && threadIdx.x == 0) *(int*)(ws + WS_CNT) = 0;
  const bool isZ = rid < Bn;
  const int r = isZ ? rid : rid - Bn;
  const float* src = (isZ ? Z : Cb) + (size_t)r * Dn + lane * 8;
  const float4 v0 = *reinterpret_cast<const float4*>(src);
  const float4 v1 = *reinterpret_cast<const float4*>(src + 4);
  float ss = v0.x * v0.x + v0.y * v0.y + v0.z * v0.z + v0.w * v0.w +
             v1.x * v1.x + v1.y * v1.y + v1.z * v1.z + v1.w * v1.w;
#pragma unroll
  for (int off = 32; off; off >>= 1) ss += __shfl_xor(ss, off);
  if (lane == 0) {
    if (isZ) ((float*)(ws + WS_ZSQ))[r] = ss;
    else {
      ((float*)(ws + WS_CSQ))[r] = ss;
      atomicMax((int*)(ws + WS_MAX), __float_as_int(ss));  // ss>0: int order == float order
    }
  }
}

// ---------------- prep_img: wave-per-fragment, coalesced writes --------------
__global__ __launch_bounds__(256) void prep_img(const float* __restrict__ Z,
                                                const float* __restrict__ Cb,
                                                char* __restrict__ ws) {
  const int w = threadIdx.x >> 6, lane = threadIdx.x & 63;
  const int wid = blockIdx.x * 4 + w;  // 0..2303
  char* CI = ws + WS_CIMG;
  char* ZI = ws + WS_ZIMG;
  char* CE = ws + WS_CEXT;
  if (wid < 2048) {
    const bool isC = wid < 1024;
    const int f = isC ? wid : wid - 1024;
    const int koct = f & 3;
    const int grp = isC ? ((f >> 2) & 3) : ((f >> 2) & 7);
    const int blk = isC ? (f >> 4) : (f >> 5);
    const int rowbase = (isC ? blk * 128 : blk * 256) + grp * 32;
    const float* src = isC ? Cb : Z;
    char* img = isC ? CI : ZI;
    const int fr = isC ? 256 : 512;
    const int ktsel = lane & 1, rr = lane >> 1;
    const float* rowp = src + (size_t)(rowbase + rr) * Dn;
#pragma unroll
    for (int kp = 0; kp < 4; ++kp) {
      const int kt = koct * 8 + kp * 2 + ktsel;
      const float4 v0 = *reinterpret_cast<const float4*>(rowp + kt * 16);
      const float4 v1 = *reinterpret_cast<const float4*>(rowp + kt * 16 + 4);
      const float4 v2 = *reinterpret_cast<const float4*>(rowp + kt * 16 + 8);
      const float4 v3 = *reinterpret_cast<const float4*>(rowp + kt * 16 + 12);
      const float fl[16] = {v0.x, v0.y, v0.z, v0.w, v1.x, v1.y, v1.z, v1.w,
                            v2.x, v2.y, v2.z, v2.w, v3.x, v3.y, v3.z, v3.w};
      _Float16 h[16];
#pragma unroll
      for (int j = 0; j < 16; ++j) h[j] = (_Float16)fl[j];
      const half8 lo8 = {h[0], h[1], h[2], h[3], h[4], h[5], h[6], h[7]};
      const half8 hi8 = {h[8], h[9], h[10], h[11], h[12], h[13], h[14], h[15]};
      char* fb = img + ((size_t)(blk * 32 + kt) * fr + grp * 64) * 16;
      *reinterpret_cast<half8*>(fb + rr * 16) = lo8;        // kh=0 chunk
      *reinterpret_cast<half8*>(fb + 512 + rr * 16) = hi8;  // kh=1 chunk
    }
  } else {  // C ext frags (csq baked): wid 2048..2303 -> (blk 0..63, grp 0..3)
    const int e = wid - 2048;
    const int grp = e & 3, blk = e >> 2;
    half8 ev = {};
    if (lane < 32) {
      const float ss = ((const float*)(ws + WS_CSQ))[blk * 128 + grp * 32 + lane];
      const _Float16 hi = (_Float16)(-0.5f * ss);
      ev[0] = hi;
      ev[1] = (_Float16)(-0.5f * ss - (float)hi);
    }
    char* fb = CE + (size_t)(blk * 4 + grp) * 1024;
    *reinterpret_cast<half8*>(fb + lane * 16) = ev;
  }
}

// ---------------- pass1 ------------------------------------------------------
// 512 blocks (2/CU), 256 thr (4 waves: wm = cb 64-half, wn = z 128-half).
// XCD swizzle: xcd = bid&7 hosts zblks 4*xcd..+3 (1MB z slice, L2-resident).
// 64 intervals of 2 k-tiles (16 MFMA/wave); 4 x 8KB LDS buffers (pair ping-pong);
// prefetch 1 interval ahead; vmcnt(0) waits only for loads >=1 interval old.
__global__ __launch_bounds__(256, 2) void vq_pass1(char* __restrict__ ws) {
  __shared__ uint4 lds4[2048];  // 32KB
  char* lds = (char*)lds4;
  const int t = threadIdx.x, lane = t & 63, w = t >> 6;
  const int wm = w >> 1, wn = w & 1;
  const int bid = blockIdx.x;
  const int zblk = (bid & 7) * 4 + ((bid >> 3) & 3);
  const int split = bid >> 5;
  const int r31 = lane & 31, kh = lane >> 5;
  const size_t l16 = (size_t)lane * 16;

  const char* zsrcT = ws + WS_ZIMG + (size_t)zblk * 262144 + (size_t)w * 2048 + l16;
  char* const ldsW = lds + w * 2048;
  const char* APb = ws + WS_CIMG + (size_t)split * 524288 + wm * 2048 + l16;
  const char* EbT = ws + WS_CEXT + (size_t)split * 16384 + wm * 2048 + l16;
  const char* ldsRd = lds + wn * 4096 + kh * 512 + r31 * 16;

  half8 aset[4][2], aE[2];
  half8 bext = {};
  if (kh == 0) { bext[0] = (_Float16)1.f; bext[1] = (_Float16)1.f; }

  float qm1[4], qm2[4], qm3[4];
  int qi1[4], qi2[4];
#pragma unroll
  for (int nb = 0; nb < 4; ++nb) {
    qm1[nb] = -3e38f; qm2[nb] = -3e38f; qm3[nb] = -3e38f;
    qi1[nb] = 0x7fffffff; qi2[nb] = 0x7fffffff;
  }
  f32x16 acc[2][4] = {};

#define GLDS(S, D) __builtin_amdgcn_global_load_lds((as1_cvoid*)(S), (as3_void*)(D), 16, 0, 0)

  // prologue: stage tiles 0,1 -> buffers 0,1; A(0),A(1); ext(p0)
  GLDS(zsrcT, ldsW); GLDS(zsrcT + 1024, ldsW + 1024);
  GLDS(zsrcT + 8192, ldsW + 8192); GLDS(zsrcT + 8192 + 1024, ldsW + 8192 + 1024);
  aset[0][0] = *reinterpret_cast<const half8*>(APb);
  aset[0][1] = *reinterpret_cast<const half8*>(APb + 1024);
  aset[1][0] = *reinterpret_cast<const half8*>(APb + 4096);
  aset[1][1] = *reinterpret_cast<const half8*>(APb + 4096 + 1024);
  aE[0] = *reinterpret_cast<const half8*>(EbT);
  aE[1] = *reinterpret_cast<const half8*>(EbT + 1024);
  asm volatile("s_waitcnt vmcnt(0)" ::: "memory");
  __builtin_amdgcn_s_barrier();

#pragma unroll 2
  for (int iv = 0; iv < 64; ++iv) {
    // ---- prefetch next interval (tiles 2iv+2, 2iv+3) ----
    if (iv < 63) {
#pragma unroll
      for (int j = 0; j < 2; ++j) {
        const int ft = 2 * iv + 2 + j;
        const char* zs = zsrcT + (size_t)(ft & 31) * 8192;
        char* zd = ldsW + (ft & 3) * 8192;
        GLDS(zs, zd); GLDS(zs + 1024, zd + 1024);
      }
#pragma unroll
      for (int j = 0; j < 2; ++j) {
        const int ft = 2 * iv + 2 + j;
        const char* s = APb + (size_t)ft * 4096;
        aset[ft & 3][0] = *reinterpret_cast<const half8*>(s);
        aset[ft & 3][1] = *reinterpret_cast<const half8*>(s + 1024);
      }
    }
    // ---- compute: 2 k-tiles, 16 MFMA ----
    __builtin_amdgcn_s_setprio(1);
#pragma unroll
    for (int j = 0; j < 2; ++j) {
      const int ft = 2 * iv + j;
      const char* bb = ldsRd + (ft & 3) * 8192;
      const half8 b0 = *reinterpret_cast<const half8*>(bb);
      const half8 b1 = *reinterpret_cast<const half8*>(bb + 1024);
      const half8 b2 = *reinterpret_cast<const half8*>(bb + 2048);
      const half8 b3 = *reinterpret_cast<const half8*>(bb + 3072);
      const half8 a0 = aset[ft & 3][0];
      const half8 a1 = aset[ft & 3][1];
      acc[0][0] = MFMA16(a0, b0, acc[0][0], 0, 0, 0);
      acc[0][1] = MFMA16(a0, b1, acc[0][1], 0, 0, 0);
      acc[0][2] = MFMA16(a0, b2, acc[0][2], 0, 0, 0);
      acc[0][3] = MFMA16(a0, b3, acc[0][3], 0, 0, 0);
      acc[1][0] = MFMA16(a1, b0, acc[1][0], 0, 0, 0);
      acc[1][1] = MFMA16(a1, b1, acc[1][1], 0, 0, 0);
      acc[1][2] = MFMA16(a1, b2, acc[1][2], 0, 0, 0);
      acc[1][3] = MFMA16(a1, b3, acc[1][3], 0, 0, 0);
    }
    __builtin_amdgcn_s_setprio(0);
    // ---- panel end: ext MFMA + in-lane top-3 fold (overlaps load latency) ----
    if ((iv & 15) == 15) {
      const int p = iv >> 4;
#pragma unroll
      for (int nb = 0; nb < 4; ++nb) {
        acc[0][nb] = MFMA16(aE[0], bext, acc[0][nb], 0, 0, 0);
        acc[1][nb] = MFMA16(aE[1], bext, acc[1][nb], 0, 0, 0);
      }
      const int cb = split * 512 + p * 128 + wm * 64 + 4 * kh;
#pragma unroll
      for (int nb = 0; nb < 4; ++nb) {
        float m1 = qm1[nb], m2 = qm2[nb], m3 = qm3[nb];
        int i1 = qi1[nb], i2 = qi2[nb];
#pragma unroll
        for (int ms = 0; ms < 2; ++ms)
#pragma unroll
          for (int r = 0; r < 16; ++r) {
            const float a = acc[ms][nb][r];
            const int ci = cb + ms * 32 + (r & 3) + 8 * (r >> 2);
            const bool b1 = (a > m1) || (a == m1 && ci < i1);
            const bool b2 = (a > m2) || (a == m2 && ci < i2);
            m3 = b2 ? m2 : fmaxf(m3, a);
            if (b1) { m2 = m1; i2 = i1; m1 = a; i1 = ci; }
            else if (b2) { m2 = a; i2 = ci; }
          }
        qm1[nb] = m1; qm2[nb] = m2; qm3[nb] = m3; qi1[nb] = i1; qi2[nb] = i2;
        acc[0][nb] = (f32x16)0.f;
        acc[1][nb] = (f32x16)0.f;
      }
      if (p < 3) {
        aE[0] = *reinterpret_cast<const half8*>(EbT + (p + 1) * 4096);
        aE[1] = *reinterpret_cast<const half8*>(EbT + (p + 1) * 4096 + 1024);
      }
    }
    // loads waited on here were issued >= 1 interval (~1000 cyc) ago -> ~free
    asm volatile("s_waitcnt vmcnt(0)" ::: "memory");
    __builtin_amdgcn_s_barrier();
  }

  // write per-bucket top-3 (score space: s = -2*m)
  float4* p1 = (float4*)(ws + WS_P1);
  float2* p3 = (float2*)(ws + WS_P3);
  const int bucket = split * 4 + wm * 2 + kh;
#pragma unroll
  for (int nb = 0; nb < 4; ++nb) {
    const int row = zblk * 256 + wn * 128 + nb * 32 + r31;
    p1[(size_t)row * 64 + bucket] =
        make_float4(-2.f * qm1[nb], (float)qi1[nb], -2.f * qm2[nb], (float)qi2[nb]);
    p3[(size_t)row * 64 + bucket] = make_float2(-2.f * qm3[nb], 0.f);
  }
#undef GLDS
}

// ---------------- gather: certify / exact-rescore pool / flag ----------------
__global__ __launch_bounds__(256) void gather_finalize(const float* __restrict__ Z,
                                                       const float* __restrict__ Cb,
                                                       char* __restrict__ ws,
                                                       float* __restrict__ zq,
                                                       float* __restrict__ idx_out) {
  const int w = threadIdx.x >> 6, l = threadIdx.x & 63;
  const int row = blockIdx.x * 4 + w;
  const float4 q = ((const float4*)(ws + WS_P1))[(size_t)row * 64 + l];
  const float s3 = ((const float2*)(ws + WS_P3))[(size_t)row * 64 + l].x;
  float s1 = q.x;
  int i1 = (int)q.y;
#pragma unroll
  for (int off = 1; off <= 32; off <<= 1) {
    const float os = __shfl_xor(s1, off); const int oi = __shfl_xor(i1, off);
    if (os < s1 || (os == s1 && oi < i1)) { s1 = os; i1 = oi; }
  }
  const float zs = ((const float*)(ws + WS_ZSQ))[row];
  const float cmax = __int_as_float(*(const int*)(ws + WS_MAX));
  // 2*eps: 2*(2^-10*||z||*||c||max + accum slack)
  const float thr = s1 + 4.0e-3f * sqrtf(zs * cmax) + 0.10f;
  int cnt = (q.x <= thr ? 1 : 0) + (q.z <= thr ? 1 : 0);
  int hide = (s3 <= thr) ? 1 : 0;
#pragma unroll
  for (int off = 1; off <= 32; off <<= 1) {
    cnt += __shfl_xor(cnt, off);
    hide |= __shfl_xor(hide, off);
  }
  if (cnt > 6 || hide) {
    if (l == 0) {
      const int pos = atomicAdd((int*)(ws + WS_CNT), 1);
      if (pos < Bn) ((int*)(ws + WS_WL))[pos] = row;
    }
    return;  // rescue writes this row
  }
  int winner = i1;
  if (cnt > 1) {  // exact fp32 rescore of the full visible pool (<=6)
    const float* csq = (const float*)(ws + WS_CSQ);
    const float4 z0 = *reinterpret_cast<const float4*>(Z + (size_t)row * Dn + l * 8);
    const float4 z1 = *reinterpret_cast<const float4*>(Z + (size_t)row * Dn + l * 8 + 4);
    float pa_s = (q.x <= thr) ? q.x : 3e38f;
    float pb_s = (q.z <= thr) ? q.z : 3e38f;
    const int pa_i = (int)q.y, pb_i = (int)q.w;
    float best_s = 3e38f;
    int best_i = 0x7fffffff;
    for (int it = 0; it < 6; ++it) {
      float cs_; int ci_;
      if (pb_s < pa_s || (pb_s == pa_s && pb_i < pa_i)) { cs_ = pb_s; ci_ = pb_i; }
      else { cs_ = pa_s; ci_ = pa_i; }
#pragma unroll
      for (int off = 1; off <= 32; off <<= 1) {
        const float os = __shfl_xor(cs_, off); const int oi = __shfl_xor(ci_, off);
        if (os < cs_ || (os == cs_ && oi < ci_)) { cs_ = os; ci_ = oi; }
      }
      if (cs_ > thr) break;  // uniform
      if (ci_ == pa_i) pa_s = 3e38f;
      if (ci_ == pb_i) pb_s = 3e38f;
      const float4 c0 = *reinterpret_cast<const float4*>(Cb + (size_t)ci_ * Dn + l * 8);
      const float4 c1 = *reinterpret_cast<const float4*>(Cb + (size_t)ci_ * Dn + l * 8 + 4);
      float pa = z0.x * c0.x + z0.y * c0.y + z0.z * c0.z + z0.w * c0.w +
                 z1.x * c1.x + z1.y * c1.y + z1.z * c1.z + z1.w * c1.w;
#pragma unroll
      for (int off = 1; off <= 32; off <<= 1) pa += __shfl_xor(pa, off);
      const float se = csq[ci_] - 2.f * pa;
      if (se < best_s || (se == best_s && ci_ < best_i)) { best_s = se; best_i = ci_; }
    }
    winner = best_i;
  }
  const float4 o0 = *reinterpret_cast<const float4*>(Cb + (size_t)winner * Dn + l * 8);
  const float4 o1 = *reinterpret_cast<const float4*>(Cb + (size_t)winner * Dn + l * 8 + 4);
  *reinterpret_cast<float4*>(zq + (size_t)row * Dn + l * 8) = o0;
  *reinterpret_cast<float4*>(zq + (size_t)row * Dn + l * 8 + 4) = o1;
  if (l == 0) idx_out[row] = (float)winner;
}

// ---------------- rescue1: exact fp32 scores for flagged rows ----------------
__global__ __launch_bounds__(256) void rescue1(const float* __restrict__ Z,
                                               const float* __restrict__ Cb,
                                               char* __restrict__ ws) {
  const int cntRaw = *(const int*)(ws + WS_CNT);
  const int cnt = cntRaw > Bn ? Bn : cntRaw;
  if (cnt == 0) return;
  const int tiles_r = (cnt + 63) >> 6;
  const int total = tiles_r * 128;
  const int* wl = (const int*)(ws + WS_WL);
  const float* csq = (const float*)(ws + WS_CSQ);
  float2* p2 = (float2*)(ws + WS_P2R);
  __shared__ float As[32][68];
  __shared__ float Bs[32][68];
  __shared__ int wlrows[64];
  const int t = threadIdx.x;
  const int tx = t & 15, ty = t >> 4;
  const int sr = t >> 3, sc = (t & 7) * 4;
  for (int tile = blockIdx.x; tile < total; tile += gridDim.x) {
    const int tr = tile >> 7, tc = tile & 127;
    __syncthreads();
    if (t < 64) {
      const int wi = tr * 64 + t;
      wlrows[t] = wl[wi < cnt ? wi : cnt - 1];
    }
    __syncthreads();
    float acc[4][4] = {};
    for (int k0 = 0; k0 < Dn; k0 += 32) {
#pragma unroll
      for (int rr = 0; rr < 2; ++rr) {
        const int m = sr + rr * 32;
        const float4 v = *reinterpret_cast<const float4*>(Z + (size_t)wlrows[m] * Dn + k0 + sc);
        As[sc + 0][m] = v.x; As[sc + 1][m] = v.y; As[sc + 2][m] = v.z; As[sc + 3][m] = v.w;
        const float4 u = *reinterpret_cast<const float4*>(Cb + (size_t)(tc * 64 + m) * Dn + k0 + sc);
        Bs[sc + 0][m] = u.x; Bs[sc + 1][m] = u.y; Bs[sc + 2][m] = u.z; Bs[sc + 3][m] = u.w;
      }
      __syncthreads();
#pragma unroll
      for (int k = 0; k < 32; ++k) {
        const float4 a = *reinterpret_cast<const float4*>(&As[k][ty * 4]);
        const float4 b = *reinterpret_cast<const float4*>(&Bs[k][tx * 4]);
        acc[0][0] += a.x * b.x; acc[0][1] += a.x * b.y; acc[0][2] += a.x * b.z; acc[0][3] += a.x * b.w;
        acc[1][0] += a.y * b.x; acc[1][1] += a.y * b.y; acc[1][2] += a.y * b.z; acc[1][3] += a.y * b.w;
        acc[2][0] += a.z * b.x; acc[2][1] += a.z * b.y; acc[2][2] += a.z * b.z; acc[2][3] += a.z * b.w;
        acc[3][0] += a.w * b.x; acc[3][1] += a.w * b.y; acc[3][2] += a.w * b.z; acc[3][3] += a.w * b.w;
      }
      __syncthreads();
    }
#pragma unroll
    for (int i = 0; i < 4; ++i) {
      float bsv = 3e38f;
      int bi = 0;
#pragma unroll
      for (int j = 0; j < 4; ++j) {
        const int n = tc * 64 + tx * 4 + j;
        const float s = csq[n] - 2.f * acc[i][j];
        if (s < bsv || (s == bsv && n < bi)) { bsv = s; bi = n; }
      }
#pragma unroll
      for (int off = 1; off <= 8; off <<= 1) {
        const float os = __shfl_xor(bsv, off); const int oi = __shfl_xor(bi, off);
        if (os < bsv || (os == bsv && oi < bi)) { bsv = os; bi = oi; }
      }
      if (tx == 0) p2[(size_t)(tr * 64 + ty * 4 + i) * 128 + tc] = make_float2(bsv, (float)bi);
    }
  }
}

// ---------------- rescue2: combine col-tile minima + write -------------------
__global__ __launch_bounds__(64) void rescue2(const float* __restrict__ Cb,
                                              char* __restrict__ ws,
                                              float* __restrict__ zq,
                                              float* __restrict__ idx_out) {
  const int cntRaw = *(const int*)(ws + WS_CNT);
  const int cnt = cntRaw > Bn ? Bn : cntRaw;
  const int* wl = (const int*)(ws + WS_WL);
  const float2* p2 = (const float2*)(ws + WS_P2R);
  const int l = threadIdx.x;
  for (int rr = blockIdx.x; rr < cnt; rr += gridDim.x) {
    const int row = wl[rr];
    const float2 e1 = p2[(size_t)rr * 128 + l];
    const float2 e2 = p2[(size_t)rr * 128 + 64 + l];
    float bs_ = e1.x;
    int bi_ = (int)e1.y;
    if (e2.x < bs_ || (e2.x == bs_ && (int)e2.y < bi_)) { bs_ = e2.x; bi_ = (int)e2.y; }
#pragma unroll
    for (int off = 1; off <= 32; off <<= 1) {
      const float os = __shfl_xor(bs_, off); const int oi = __shfl_xor(bi_, off);
      if (os < bs_ || (os == bs_ && oi < bi_)) { bs_ = os; bi_ = oi; }
    }
    const float4 c0 = *reinterpret_cast<const float4*>(Cb + (size_t)bi_ * Dn + l * 8);
    const float4 c1 = *reinterpret_cast<const float4*>(Cb + (size_t)bi_ * Dn + l * 8 + 4);
    *reinterpret_cast<float4*>(zq + (size_t)row * Dn + l * 8) = c0;
    *reinterpret_cast<float4*>(zq + (size_t)row * Dn + l * 8 + 4) = c1;
    if (l == 0) idx_out[row] = (float)bi_;
  }
}

extern "C" void kernel_launch(void* const* d_in, const int* in_sizes, int n_in,
                              void* d_out, int out_size, void* d_ws, size_t ws_size,
                              hipStream_t stream) {
  const float* Z = (const float*)d_in[0];  // [B, D]
  const float* C = (const float*)d_in[1];  // [K, D]
  float* out = (float*)d_out;              // [B*D] z_q then [B] indices
  char* ws = (char*)d_ws;                  // ~29.3MB

  prep_sums<<<4096, 256, 0, stream>>>(Z, C, ws);
  prep_img<<<576, 256, 0, stream>>>(Z, C, ws);
  vq_pass1<<<512, 256, 0, stream>>>(ws);
  gather_finalize<<<2048, 256, 0, stream>>>(Z, C, ws, out, out + (size_t)Bn * Dn);
  rescue1<<<512, 256, 0, stream>>>(Z, C, ws);
  rescue2<<<256, 64, 0, stream>>>(C, ws, out, out + (size_t)Bn * Dn);
}